// Round 7
// baseline (55.077 us; speedup 1.0000x reference)
//
#include <hip/hip_runtime.h>

// GaussianAntecedent: out[n,r] = mem[n,r] / (sum_r mem[n,r] + 1e-8)
// mem = exp2( sum_d max( -(q*x + pn)^2 , L ) ),
//   q = sqrt(0.5*log2 e)/(sigma+eps), pn = -c*q, L = log2(1e-8) < 0
//
// lane = rule (R=64 == wavefront). Per-lane constants in VGPRs.
// R6 post-mortem: compiler scalarized X loads (VGPR 48 / SGPR 96) --
// X rows live in SGPRs; still latency-bound at occ 27% because the grid
// supplies only 6250 waves (6/SIMD). R7: single-variable change --
// ROWS_PER_WAVE 16 -> 4 => 25000 waves (~97/CU demand, ~3 occupancy
// fills at 32 waves/CU). Cost: const prologue amortized over 4 rows
// instead of 16 (~+8% instructions). Everything else unchanged.

typedef float v2f __attribute__((ext_vector_type(2)));

constexpr int DDIM = 32;
constexpr int RR   = 64;
constexpr int RPW  = 4;   // rows per wave (N=100000 -> 25000 waves, no tail)
constexpr int WPB  = 4;   // waves per block

__device__ inline float fast_exp2(float x) {
#if __has_builtin(__builtin_amdgcn_exp2f)
    return __builtin_amdgcn_exp2f(x);
#else
    return exp2f(x);
#endif
}

template <int CTRL>
__device__ inline float dpp_add(float x) {
    int t = __builtin_amdgcn_update_dpp(0, __float_as_int(x), CTRL, 0xF, 0xF, true);
    return x + __int_as_float(t);
}

// Wave64 sum, result broadcast to all lanes via SGPR.
__device__ inline float wave_sum_bcast(float x) {
    x = dpp_add<0x111>(x);  // row_shr:1
    x = dpp_add<0x112>(x);  // row_shr:2
    x = dpp_add<0x114>(x);  // row_shr:4
    x = dpp_add<0x118>(x);  // row_shr:8
    x = dpp_add<0x142>(x);  // row_bcast:15
    x = dpp_add<0x143>(x);  // row_bcast:31
    return __int_as_float(__builtin_amdgcn_readlane(__float_as_int(x), 63));
}

__global__ __launch_bounds__(256, 4) void gauss_antecedent_kernel(
    const float* __restrict__ X,
    const float* __restrict__ centers,
    const float* __restrict__ sigma,
    float* __restrict__ out, int N)
{
    const int lane = threadIdx.x & 63;
    const int wid  = blockIdx.x * WPB + (threadIdx.x >> 6);
    const int row0 = wid * RPW;
    if (row0 >= N) return;

    const float SQK = 0.84932180028801907f;   // sqrt(0.5 * log2(e))
    const float LC  = -26.575424759098897f;   // log2(1e-8)

    // Per-lane (rule = lane) constants, held in VGPR pairs.
    v2f q2[DDIM / 2], pn2[DDIM / 2];
    #pragma unroll
    for (int d = 0; d < DDIM; d += 4) {
        float4 cc = *reinterpret_cast<const float4*>(&centers[lane * DDIM + d]);
        float4 ss = *reinterpret_cast<const float4*>(&sigma[lane * DDIM + d]);
        float qa = SQK / (ss.x + 1e-8f);
        float qb = SQK / (ss.y + 1e-8f);
        float qc = SQK / (ss.z + 1e-8f);
        float qd = SQK / (ss.w + 1e-8f);
        q2[d / 2 + 0] = (v2f){qa, qb};
        q2[d / 2 + 1] = (v2f){qc, qd};
        pn2[d / 2 + 0] = (v2f){-cc.x * qa, -cc.y * qb};
        pn2[d / 2 + 1] = (v2f){-cc.z * qc, -cc.w * qd};
    }
    const v2f L2 = {LC, LC};

    if (row0 + RPW <= N) {
        const int r0s = __builtin_amdgcn_readfirstlane(row0);
        const float4* __restrict__ xbase =
            reinterpret_cast<const float4*>(X + (size_t)r0s * DDIM);

        // prologue: load first pair of rows (16 x float4 = 2 rows).
        // Wave-uniform address -> compiler emits scalar s_loads (SGPRs).
        float4 cur[16];
        #pragma unroll
        for (int j = 0; j < 16; ++j) cur[j] = xbase[j];

        #pragma unroll
        for (int p = 0; p < RPW / 2; ++p) {
            // ---- compute: 2 rows, negative clamped log2-sums ----
            v2f Ba[2] = {{0.f, 0.f}, {0.f, 0.f}};
            v2f Bb[2] = {{0.f, 0.f}, {0.f, 0.f}};
            #pragma unroll
            for (int j = 0; j < 8; ++j) {
                float4 a = cur[j], b = cur[8 + j];
                v2f a0 = {a.x, a.y}, a1 = {a.z, a.w};
                v2f b0 = {b.x, b.y}, b1 = {b.z, b.w};
                v2f ta0 = __builtin_elementwise_fma(q2[2*j],   a0, pn2[2*j]);
                v2f ta1 = __builtin_elementwise_fma(q2[2*j+1], a1, pn2[2*j+1]);
                v2f tb0 = __builtin_elementwise_fma(q2[2*j],   b0, pn2[2*j]);
                v2f tb1 = __builtin_elementwise_fma(q2[2*j+1], b1, pn2[2*j+1]);
                // B = max(B - t*t, B + L)  (exact: B + max(-t^2, L))
                v2f ua0 = __builtin_elementwise_fma(ta0, -ta0, Ba[0]);
                v2f ua1 = __builtin_elementwise_fma(ta1, -ta1, Ba[1]);
                v2f ub0 = __builtin_elementwise_fma(tb0, -tb0, Bb[0]);
                v2f ub1 = __builtin_elementwise_fma(tb1, -tb1, Bb[1]);
                Ba[0] = __builtin_elementwise_max(ua0, Ba[0] + L2);
                Ba[1] = __builtin_elementwise_max(ua1, Ba[1] + L2);
                Bb[0] = __builtin_elementwise_max(ub0, Bb[0] + L2);
                Bb[1] = __builtin_elementwise_max(ub1, Bb[1] + L2);
            }

            // ---- prefetch next pair BEFORE the epilogue ----
            float4 nxt[16];
            if (p < RPW / 2 - 1) {
                const float4* __restrict__ nb = xbase + (p + 1) * 16;
                #pragma unroll
                for (int j = 0; j < 16; ++j) nxt[j] = nb[j];
            }

            // ---- epilogue: exp2, DPP wave-sum, normalize, store ----
            v2f sa = Ba[0] + Ba[1];
            v2f sb = Bb[0] + Bb[1];
            float ma = fast_exp2(sa.x + sa.y);
            float mb = fast_exp2(sb.x + sb.y);
            float Sa = wave_sum_bcast(ma);
            float Sb = wave_sum_bcast(mb);
            const size_t o = (size_t)(r0s + 2 * p) * RR + lane;
            out[o]      = ma * __builtin_amdgcn_rcpf(Sa + 1e-8f);
            out[o + RR] = mb * __builtin_amdgcn_rcpf(Sb + 1e-8f);

            if (p < RPW / 2 - 1) {
                #pragma unroll
                for (int j = 0; j < 16; ++j) cur[j] = nxt[j];
            }
        }
    } else {
        // ---- tail path (not taken for N=100000) ----
        for (int n = row0; n < N; ++n) {
            const int ns = __builtin_amdgcn_readfirstlane(n);
            const float4* __restrict__ xr =
                reinterpret_cast<const float4*>(X + (size_t)ns * DDIM);
            v2f B[2] = {{0.f, 0.f}, {0.f, 0.f}};
            #pragma unroll
            for (int j = 0; j < 8; ++j) {
                float4 xj = xr[j];
                v2f a0 = {xj.x, xj.y}, a1 = {xj.z, xj.w};
                v2f t0 = __builtin_elementwise_fma(q2[2*j],   a0, pn2[2*j]);
                v2f t1 = __builtin_elementwise_fma(q2[2*j+1], a1, pn2[2*j+1]);
                v2f u0 = __builtin_elementwise_fma(t0, -t0, B[0]);
                v2f u1 = __builtin_elementwise_fma(t1, -t1, B[1]);
                B[0] = __builtin_elementwise_max(u0, B[0] + L2);
                B[1] = __builtin_elementwise_max(u1, B[1] + L2);
            }
            v2f s = B[0] + B[1];
            float mem = fast_exp2(s.x + s.y);
            float S = wave_sum_bcast(mem);
            out[(size_t)ns * RR + lane] = mem * __builtin_amdgcn_rcpf(S + 1e-8f);
        }
    }
}

extern "C" void kernel_launch(void* const* d_in, const int* in_sizes, int n_in,
                              void* d_out, int out_size, void* d_ws, size_t ws_size,
                              hipStream_t stream) {
    const float* X       = (const float*)d_in[0];
    const float* centers = (const float*)d_in[1];
    const float* sigma   = (const float*)d_in[2];
    float* out = (float*)d_out;

    const int N = in_sizes[0] / DDIM;  // 100000
    const int nwaves = (N + RPW - 1) / RPW;
    const int grid = (nwaves + WPB - 1) / WPB;

    gauss_antecedent_kernel<<<grid, 256, 0, stream>>>(X, centers, sigma, out, N);
}